// Round 7
// baseline (378.487 us; speedup 1.0000x reference)
//
#include <hip/hip_runtime.h>
#include <hip/hip_bf16.h>

typedef __bf16 bf16_t;
typedef bf16_t bf16x8 __attribute__((ext_vector_type(8)));
typedef bf16_t bf16x4 __attribute__((ext_vector_type(4)));
typedef float f32x4 __attribute__((ext_vector_type(4)));

#define N_TOK 4096
#define DIM   768
#define HID   3072
#define NEXP  8
#define PADROWS 9216   // 8192 + 8*128 headroom for per-expert 128-padding
#define MMAX  32       // 128-row m-tiles per expert (gemm1)
#define MT2   64       // 64-row m-tiles per expert (gemm2)

// ---------------- ws layout (bytes) ----------------
#define OFF_COUNTS 0
#define OFF_PSUM   32
#define OFF_OFFPAD 64      // int off_pad[9]
#define OFF_CURSOR 128
#define OFF_TOKE   256                         // int[8192]
#define OFF_TOKW   (OFF_TOKE + 4*8192)         // float[8192]
#define OFF_PERMT  (OFF_TOKW + 4*8192)         // int[PADROWS]  (also cs_part)
#define OFF_PERMW  (OFF_PERMT + 4*PADROWS)     // float[PADROWS] (ps_part, then inv_pos)
#define OFF_XP     (((OFF_PERMW + 4*PADROWS) + 511) & ~511ull)  // bf16[PADROWS*DIM] (xp, then y)
#define OFF_H      (OFF_XP + 2ull*PADROWS*DIM)                  // bf16[PADROWS*HID]
#define WS_NEEDED  (OFF_H + 2ull*PADROWS*HID)

#define GATE_BLOCKS (N_TOK / 4)        // 1024
#define GEMM1_BLOCKS (8 * 24 * MMAX)   // 6144

// ---------------- async global->LDS 16B ----------------
__device__ __forceinline__ void async_copy16(const bf16_t* g, bf16_t* l) {
    __builtin_amdgcn_global_load_lds(
        (const __attribute__((address_space(1))) void*)g,
        (__attribute__((address_space(3))) void*)l, 16, 0, 0);
}

__device__ __forceinline__ bf16x8 cvt8(float4 lo, float4 hi) {
    bf16x8 o;
    o[0] = (bf16_t)lo.x; o[1] = (bf16_t)lo.y; o[2] = (bf16_t)lo.z; o[3] = (bf16_t)lo.w;
    o[4] = (bf16_t)hi.x; o[5] = (bf16_t)hi.y; o[6] = (bf16_t)hi.z; o[7] = (bf16_t)hi.w;
    return o;
}

// ---------------- gate: one wave per token, atomic-free partials ----------------
// No weight-conversion pass anymore: the GEMMs read fp32 weights directly and
// convert during LDS staging (removes 151MB fp32 read + 75.5MB bf16 write +
// 75.5MB bf16 re-read round-trip and the serialized conv phase).
__global__ __launch_bounds__(256) void gate_kernel(
    const float* __restrict__ x, const float* __restrict__ gw,
    int* __restrict__ cs_part, float* __restrict__ ps_part,
    int* __restrict__ tok_e, float* __restrict__ tok_w)
{
    __shared__ float ps[8];
    __shared__ int cs[8];
    if (threadIdx.x < 8) { ps[threadIdx.x] = 0.f; cs[threadIdx.x] = 0; }
    __syncthreads();

    const int bid = blockIdx.x;
    const int wv = threadIdx.x >> 6, lane = threadIdx.x & 63;
    const int n = bid * 4 + wv;

    float acc[8];
#pragma unroll
    for (int e = 0; e < 8; e++) acc[e] = 0.f;
    const float* xr = x + (size_t)n * DIM;
#pragma unroll
    for (int c = 0; c < 12; c++) {
        const float xv = xr[c * 64 + lane];
#pragma unroll
        for (int e = 0; e < 8; e++) acc[e] += xv * gw[e * DIM + c * 64 + lane];
    }
#pragma unroll
    for (int e = 0; e < 8; e++)
        for (int off = 32; off > 0; off >>= 1) acc[e] += __shfl_xor(acc[e], off, 64);

    float mx = acc[0];
#pragma unroll
    for (int e = 1; e < 8; e++) mx = fmaxf(mx, acc[e]);
    float p[8], s = 0.f;
#pragma unroll
    for (int e = 0; e < 8; e++) { p[e] = expf(acc[e] - mx); s += p[e]; }

    int e1 = 0;
#pragma unroll
    for (int e = 1; e < 8; e++) if (p[e] > p[e1]) e1 = e;
    int e2 = (e1 == 0) ? 1 : 0;
#pragma unroll
    for (int e = 0; e < 8; e++) if (e != e1 && p[e] > p[e2]) e2 = e;
    const float denom = p[e1] + p[e2];

    if (lane == 0) {
        tok_e[2 * n] = e1; tok_e[2 * n + 1] = e2;
        tok_w[2 * n] = p[e1] / denom; tok_w[2 * n + 1] = p[e2] / denom;
        const float inv = 1.f / s;
#pragma unroll
        for (int e = 0; e < 8; e++) atomicAdd(&ps[e], p[e] * inv);  // LDS-only
        atomicAdd(&cs[e1], 1); atomicAdd(&cs[e2], 1);               // LDS-only
    }
    __syncthreads();
    if (threadIdx.x < 8) {
        ps_part[bid * 8 + threadIdx.x] = ps[threadIdx.x];
        cs_part[bid * 8 + threadIdx.x] = cs[threadIdx.x];
    }
}

// ---------------- finalize + scatter (single block, LDS cursors) ----------------
__global__ __launch_bounds__(256) void finalize_scatter(
    const int* cs_part, const float* ps_part,
    const int* __restrict__ tok_e, const float* __restrict__ tok_w,
    int* __restrict__ counts, int* __restrict__ off_pad,
    int* perm_tok, int* inv_pos, float* __restrict__ out_loss)
{
    __shared__ float rps[256];
    __shared__ int rcs[256];
    __shared__ int s_cur[8];
    const int t = threadIdx.x;
    const int e = t & 7, chunk = t >> 3;
    float psum = 0.f; int csum = 0;
#pragma unroll
    for (int i = 0; i < 32; i++) {
        const int b = chunk * 32 + i;
        psum += ps_part[b * 8 + e];
        csum += cs_part[b * 8 + e];
    }
    rps[t] = psum; rcs[t] = csum;
    __syncthreads();
    for (int s = 128; s >= 8; s >>= 1) {
        if (t < s) { rps[t] += rps[t + s]; rcs[t] += rcs[t + s]; }
        __syncthreads();
    }
    if (t == 0) {
        int off = 0; float loss = 0.f;
        for (int k = 0; k < 8; k++) {
            counts[k] = rcs[k];
            off_pad[k] = off; s_cur[k] = off;
            off += ((rcs[k] + 127) & ~127);
            loss += rps[k] * (float)rcs[k];
        }
        off_pad[8] = off;
        *out_loss = loss * 8.f / ((float)N_TOK * (float)N_TOK);
    }
    __syncthreads();
    for (int r = 0; r < N_TOK / 256; r++) {
        const int n = r * 256 + t;
#pragma unroll
        for (int k = 0; k < 2; k++) {
            const int ee = tok_e[2 * n + k];
            const int pos = atomicAdd(&s_cur[ee], 1);   // LDS cursor
            perm_tok[pos] = n;
            inv_pos[2 * n + k] = pos;
        }
    }
}

// ---------------- gather permuted tokens, fp32 -> bf16, zero pad rows ----------------
__global__ __launch_bounds__(256) void gather_x_kernel(
    const float* __restrict__ x, const int* __restrict__ off_pad,
    const int* __restrict__ counts, const int* __restrict__ perm_tok,
    bf16_t* __restrict__ xp)
{
    __shared__ int so[9], scnt[8];
    if (threadIdx.x < 9) so[threadIdx.x] = off_pad[threadIdx.x];
    if (threadIdx.x < 8) scnt[threadIdx.x] = counts[threadIdx.x];
    __syncthreads();
    const int gid = blockIdx.x * 256 + threadIdx.x;
    const int p = gid / 192;            // padded row
    const int c = (gid - p * 192) * 4;  // column
    int e = 0;
#pragma unroll
    for (int k = 1; k < 8; k++) if (p >= so[k]) e = k;
    const bool valid = (p < so[8]) && (p - so[e] < scnt[e]);
    float4 v = make_float4(0.f, 0.f, 0.f, 0.f);
    if (valid) {
        const int tok = perm_tok[p];
        v = *(const float4*)(x + (size_t)tok * DIM + c);
    }
    bf16x4 o; o[0] = (bf16_t)v.x; o[1] = (bf16_t)v.y; o[2] = (bf16_t)v.z; o[3] = (bf16_t)v.w;
    *(bf16x4*)(xp + (size_t)p * DIM + c) = o;
}

// ---------------- GEMM1: h = relu(xp @ w_fc^T)^2 ----------------
// 128x128 tile, BK=64. A (bf16) via global_load_lds; B (fp32 weights) is
// reg-staged: global float4 loads issued BEFORE the barrier (latency overlap),
// cvt->bf16, ds_write_b128 after it. Same XOR swizzle (we control the ds_write
// address). id = xcd + 8*slot, xcd = expert; slot = n_t*MMAX + m_t.
__global__ __launch_bounds__(256, 3) void gemm1_kernel(
    const bf16_t* __restrict__ xp, const float* __restrict__ wfc,
    const int* __restrict__ off_pad, bf16_t* __restrict__ h)
{
    const int id = blockIdx.x;
    const int e = id & 7;
    const int slot = id >> 3;
    const int n_t = slot / MMAX, m_t = slot % MMAX;

    const int seg0 = off_pad[e];
    const int cnt_pad = off_pad[e + 1] - seg0;
    const int m0 = m_t * 128;
    if (m0 >= cnt_pad) return;
    const int n0 = n_t * 128;  // over HID

    __shared__ bf16_t As[128 * 64];
    __shared__ bf16_t Bs[128 * 64];

    const int t = threadIdx.x;
    const int srow = t >> 3, sc = t & 7;
    const int gsc = sc ^ (srow & 7);   // swizzled source chunk -> linear LDS slot
    const bf16_t* abase = xp + (size_t)(seg0 + m0 + srow) * DIM + gsc * 8;
    const float*  bbase = wfc + ((size_t)e * HID + n0 + srow) * DIM + gsc * 8;

    const int wv = t >> 6, lane = t & 63;
    const int lrow = lane & 15, quad = lane >> 4;
    const int wm = (wv & 1) * 64, wn = (wv >> 1) * 64;
    const int sw = lrow & 7;           // read-side swizzle key

    f32x4 acc[4][4] = {};

    for (int k0 = 0; k0 < DIM; k0 += 64) {
        // B fp32 loads issued early: global-only, no LDS hazard before barrier
        float4 blo[4], bhi[4];
#pragma unroll
        for (int ii = 0; ii < 4; ii++) {
            const float* src = bbase + (size_t)ii * 32 * DIM + k0;
            blo[ii] = *(const float4*)src;
            bhi[ii] = *(const float4*)(src + 4);
        }
        __syncthreads();
#pragma unroll
        for (int ii = 0; ii < 4; ii++)
            async_copy16(abase + (size_t)ii * 32 * DIM + k0, &As[(ii * 256 + t) * 8]);
#pragma unroll
        for (int ii = 0; ii < 4; ii++)
            *(bf16x8*)&Bs[(ii * 256 + t) * 8] = cvt8(blo[ii], bhi[ii]);
        __syncthreads();
#pragma unroll
        for (int kh = 0; kh < 2; kh++) {
            const int ch = ((kh * 4 + quad) ^ sw) * 8;
            bf16x8 af[4], bfv[4];
#pragma unroll
            for (int i = 0; i < 4; i++)
                af[i] = *(bf16x8*)&As[(wm + i * 16 + lrow) * 64 + ch];
#pragma unroll
            for (int j = 0; j < 4; j++)
                bfv[j] = *(bf16x8*)&Bs[(wn + j * 16 + lrow) * 64 + ch];
#pragma unroll
            for (int i = 0; i < 4; i++)
#pragma unroll
                for (int j = 0; j < 4; j++)
                    acc[i][j] = __builtin_amdgcn_mfma_f32_16x16x32_bf16(af[i], bfv[j], acc[i][j], 0, 0, 0);
        }
    }

    // epilogue: relu^2 -> bf16. C/D map: col=lane&15 (n), row=quad*4+reg (m).
#pragma unroll
    for (int i = 0; i < 4; i++) {
#pragma unroll
        for (int g = 0; g < 4; g++) {
            const int m = m0 + wm + i * 16 + quad * 4 + g;
            bf16_t* hrow = h + (size_t)(seg0 + m) * HID + n0 + wn + lrow;
#pragma unroll
            for (int j = 0; j < 4; j++) {
                float v = fmaxf(acc[i][j][g], 0.f);
                hrow[j * 16] = (bf16_t)(v * v);
            }
        }
    }
}

// ---------------- GEMM2: y[pos] = h[pos] @ w_proj^T  (no atomics) ----------------
// 64x128 tile, BK=128 as TWO K-panels of [rows][64] (128B stride, conflict-free).
// A (h, bf16) via global_load_lds; B (w_proj fp32) reg-staged with cvt.
// id = xcd + 8*slot, xcd = expert; slot = m_t*6 + n_t.
__global__ __launch_bounds__(256, 3) void gemm2_kernel(
    const bf16_t* __restrict__ h, const float* __restrict__ wpj,
    const int* __restrict__ off_pad, const int* __restrict__ counts,
    bf16_t* __restrict__ y)
{
    const int id = blockIdx.x;
    const int e = id & 7;
    const int slot = id >> 3;
    const int m_t = slot / 6, n_t = slot % 6;

    const int seg0 = off_pad[e];
    const int cnt = counts[e];
    const int m0 = m_t * 64;
    if (m0 >= cnt) return;
    const int n0 = n_t * 128;  // over DIM

    __shared__ bf16_t As[2][64 * 64];    // panel p: K elems [k0+p*64, k0+p*64+64)
    __shared__ bf16_t Bs[2][128 * 64];

    const int t = threadIdx.x;
    const int srow = t >> 3, sc = t & 7;
    const int gsc = sc ^ (srow & 7);
    const bf16_t* abase = h + (size_t)(seg0 + m0 + srow) * HID + gsc * 8;
    const float*  bbase = wpj + ((size_t)e * DIM + n0 + srow) * HID + gsc * 8;

    const int wv = t >> 6, lane = t & 63;
    const int lrow = lane & 15, quad = lane >> 4;
    const int wm = (wv & 1) * 32, wn = (wv >> 1) * 64;   // 2x2 waves, 32x64 each
    const int sw = lrow & 7;

    f32x4 acc[2][4] = {};

    for (int k0 = 0; k0 < HID; k0 += 128) {
        float4 blo[2][4], bhi[2][4];
#pragma unroll
        for (int p = 0; p < 2; p++)
#pragma unroll
            for (int ii = 0; ii < 4; ii++) {
                const float* src = bbase + (size_t)ii * 32 * HID + k0 + p * 64;
                blo[p][ii] = *(const float4*)src;
                bhi[p][ii] = *(const float4*)(src + 4);
            }
        __syncthreads();
#pragma unroll
        for (int p = 0; p < 2; p++)
#pragma unroll
            for (int ii = 0; ii < 2; ii++)   // A: 64 rows (2 passes of 32)
                async_copy16(abase + (size_t)ii * 32 * HID + k0 + p * 64,
                             &As[p][(ii * 256 + t) * 8]);
#pragma unroll
        for (int p = 0; p < 2; p++)
#pragma unroll
            for (int ii = 0; ii < 4; ii++)   // B: 128 rows (4 passes of 32)
                *(bf16x8*)&Bs[p][(ii * 256 + t) * 8] = cvt8(blo[p][ii], bhi[p][ii]);
        __syncthreads();
#pragma unroll
        for (int kh = 0; kh < 4; kh++) {
            const int p = kh >> 1, khh = kh & 1;
            const int ch = ((khh * 4 + quad) ^ sw) * 8;
            bf16x8 af[2], bfv[4];
#pragma unroll
            for (int i = 0; i < 2; i++)
                af[i] = *(bf16x8*)&As[p][(wm + i * 16 + lrow) * 64 + ch];
#pragma unroll
            for (int j = 0; j < 4; j++)
                bfv[j] = *(bf16x8*)&Bs[p][(wn + j * 16 + lrow) * 64 + ch];
#pragma unroll
            for (int i = 0; i < 2; i++)
#pragma unroll
                for (int j = 0; j < 4; j++)
                    acc[i][j] = __builtin_amdgcn_mfma_f32_16x16x32_bf16(af[i], bfv[j], acc[i][j], 0, 0, 0);
        }
    }

    // epilogue: plain bf16 stores, rows exclusive to this block
#pragma unroll
    for (int i = 0; i < 2; i++) {
#pragma unroll
        for (int g = 0; g < 4; g++) {
            const int m = m0 + wm + i * 16 + quad * 4 + g;
            if (m < cnt) {
                bf16_t* yrow = y + (size_t)(seg0 + m) * DIM + n0 + wn + lrow;
#pragma unroll
                for (int j = 0; j < 4; j++)
                    yrow[j * 16] = (bf16_t)acc[i][j][g];
            }
        }
    }
}

// ---------------- combine: out[n] = w1*y[p1] + w2*y[p2] ----------------
__global__ __launch_bounds__(192) void combine_kernel(
    const bf16_t* __restrict__ y, const int* __restrict__ inv_pos,
    const float* __restrict__ tok_w, float* __restrict__ out)
{
    const int n = blockIdx.x;
    const int d = threadIdx.x * 4;
    const int p1 = inv_pos[2 * n], p2 = inv_pos[2 * n + 1];
    const float w1 = tok_w[2 * n], w2 = tok_w[2 * n + 1];
    bf16x4 a = *(const bf16x4*)(y + (size_t)p1 * DIM + d);
    bf16x4 b = *(const bf16x4*)(y + (size_t)p2 * DIM + d);
    float4 o;
    o.x = w1 * (float)a[0] + w2 * (float)b[0];
    o.y = w1 * (float)a[1] + w2 * (float)b[1];
    o.z = w1 * (float)a[2] + w2 * (float)b[2];
    o.w = w1 * (float)a[3] + w2 * (float)b[3];
    *(float4*)(out + (size_t)n * DIM + d) = o;
}

extern "C" void kernel_launch(void* const* d_in, const int* in_sizes, int n_in,
                              void* d_out, int out_size, void* d_ws, size_t ws_size,
                              hipStream_t stream) {
    const float* x      = (const float*)d_in[0];
    const float* gate_w = (const float*)d_in[1];
    const float* w_fc   = (const float*)d_in[2];
    const float* w_proj = (const float*)d_in[3];
    float* out = (float*)d_out;

    if (ws_size < WS_NEEDED) return;

    char* w = (char*)d_ws;
    int*    counts    = (int*)(w + OFF_COUNTS);
    int*    off_pad   = (int*)(w + OFF_OFFPAD);
    int*    tok_e     = (int*)(w + OFF_TOKE);
    float*  tok_w     = (float*)(w + OFF_TOKW);
    int*    perm_tok  = (int*)(w + OFF_PERMT);
    int*    inv_pos   = (int*)(w + OFF_PERMW);   // ps_part then inv_pos
    bf16_t* xp        = (bf16_t*)(w + OFF_XP);   // xp, then y (gemm2 output)
    bf16_t* hbuf      = (bf16_t*)(w + OFF_H);

    int*   cs_part = perm_tok;            // int[1024*8], consumed by finalize
    float* ps_part = (float*)inv_pos;     // float[1024*8], consumed by finalize
    bf16_t* y = xp;                       // xp dead after gemm1

    // no d_out memset: combine writes every [0, N*DIM) element, loss at out_size-1.
    gate_kernel<<<GATE_BLOCKS, 256, 0, stream>>>(x, gate_w, cs_part, ps_part, tok_e, tok_w);
    finalize_scatter<<<1, 256, 0, stream>>>(cs_part, ps_part, tok_e, tok_w,
                                            counts, off_pad, perm_tok, inv_pos,
                                            out + (size_t)out_size - 1);
    gather_x_kernel<<<PADROWS * DIM / 4 / 256, 256, 0, stream>>>(x, off_pad, counts, perm_tok, xp);

    // XCD-locality 1D grids: id = xcd + 8*slot (xcd = expert).
    gemm1_kernel<<<GEMM1_BLOCKS, 256, 0, stream>>>(xp, w_fc, off_pad, hbuf);
    gemm2_kernel<<<8 * MT2 * 6, 256, 0, stream>>>(hbuf, w_proj, off_pad, counts, y);
    combine_kernel<<<N_TOK, 192, 0, stream>>>(y, inv_pos, tok_w, out);
}

// Round 8
// 317.725 us; speedup vs baseline: 1.1912x; 1.1912x over previous
//
#include <hip/hip_runtime.h>
#include <hip/hip_bf16.h>

typedef __bf16 bf16_t;
typedef bf16_t bf16x8 __attribute__((ext_vector_type(8)));
typedef bf16_t bf16x4 __attribute__((ext_vector_type(4)));
typedef float f32x4 __attribute__((ext_vector_type(4)));

#define N_TOK 4096
#define DIM   768
#define HID   3072
#define NEXP  8
#define PADROWS 9216   // 8192 + 8*128 headroom for per-expert 128-padding
#define MMAX  32       // 128-row m-tiles per expert (gemm1)
#define MT2   64       // 64-row m-tiles per expert (gemm2)

// ---------------- ws layout (bytes) ----------------
#define OFF_COUNTS 0
#define OFF_PSUM   32
#define OFF_OFFPAD 64      // int off_pad[9]
#define OFF_CURSOR 128
#define OFF_TOKE   256                         // int[8192]
#define OFF_TOKW   (OFF_TOKE + 4*8192)         // float[8192]
#define OFF_PERMT  (OFF_TOKW + 4*8192)         // int[PADROWS]  (also cs_part)
#define OFF_PERMW  (OFF_PERMT + 4*PADROWS)     // float[PADROWS] (ps_part, then inv_pos)
#define OFF_XP     (((OFF_PERMW + 4*PADROWS) + 511) & ~511ull)  // bf16[PADROWS*DIM] (xp, then y)
#define OFF_WFC    (OFF_XP + 2ull*PADROWS*DIM)                  // bf16[8*HID*DIM]
#define OFF_WPJ    (OFF_WFC + 2ull*NEXP*HID*DIM)                // bf16[8*DIM*HID]
#define OFF_H      (OFF_WPJ + 2ull*NEXP*DIM*HID)                // bf16[PADROWS*HID]
#define WS_NEEDED  (OFF_H + 2ull*PADROWS*HID)

#define GATE_BLOCKS (N_TOK / 4)    // 1024
#define CONVH_BLOCKS 4608          // blocks to convert ONE weight tensor
#define GEMM1_BLOCKS (8 * 24 * MMAX)   // 6144

// ---------------- async global->LDS 16B ----------------
__device__ __forceinline__ void async_copy16(const bf16_t* g, bf16_t* l) {
    __builtin_amdgcn_global_load_lds(
        (const __attribute__((address_space(1))) void*)g,
        (__attribute__((address_space(3))) void*)l, 16, 0, 0);
}

// ---------------- fp32 -> bf16 tensor convert, fully coalesced ----------------
// NOTE (R7 lesson): do NOT fold this into the GEMMs. fp32-direct weights double
// HBM bytes and per-expert fp32 panels (9.4MB) overflow the 4MB XCD L2 ->
// gemm2 went 71->144us. Pre-converted bf16 + global_load_lds is the winner.
__device__ __forceinline__ void convert_chunk(const float* __restrict__ src,
                                              bf16_t* __restrict__ dst,
                                              int cid, int t) {
    const long long base = (long long)cid * 256 + t;          // float4 index
    const long long stride = (long long)CONVH_BLOCKS * 256;   // 1179648
    // 18874368 floats / 4 = 4718592 float4 = exactly 4 * stride
#pragma unroll
    for (int it = 0; it < 4; it++) {
        const long long i4 = base + (long long)it * stride;
        float4 v = *((const float4*)src + i4);
        bf16x4 o;
        o[0] = (bf16_t)v.x; o[1] = (bf16_t)v.y;
        o[2] = (bf16_t)v.z; o[3] = (bf16_t)v.w;
        *(bf16x4*)(dst + i4 * 4) = o;
    }
}

// ---------------- fused prep: gating + w_fc convert ----------------
// blocks [0, GATE_BLOCKS): gate, one wave per token.
// blocks [GATE_BLOCKS, +CONVH_BLOCKS): convert w_fc only (w_proj conversion
// rides inside the gemm1 launch; stream order guarantees done before gemm2).
__global__ __launch_bounds__(256) void prep_kernel(
    const float* __restrict__ w_fc, bf16_t* __restrict__ wfc_b,
    const float* __restrict__ x, const float* __restrict__ gw,
    int* __restrict__ cs_part, float* __restrict__ ps_part,
    int* __restrict__ tok_e, float* __restrict__ tok_w)
{
    __shared__ float ps[8];
    __shared__ int cs[8];

    if (blockIdx.x >= GATE_BLOCKS) {
        convert_chunk(w_fc, wfc_b, blockIdx.x - GATE_BLOCKS, threadIdx.x);
        return;
    }

    // ---- gate path ----
    if (threadIdx.x < 8) { ps[threadIdx.x] = 0.f; cs[threadIdx.x] = 0; }
    __syncthreads();

    const int bid = blockIdx.x;
    const int wv = threadIdx.x >> 6, lane = threadIdx.x & 63;
    const int n = bid * 4 + wv;

    float acc[8];
#pragma unroll
    for (int e = 0; e < 8; e++) acc[e] = 0.f;
    const float* xr = x + (size_t)n * DIM;
#pragma unroll
    for (int c = 0; c < 12; c++) {
        const float xv = xr[c * 64 + lane];
#pragma unroll
        for (int e = 0; e < 8; e++) acc[e] += xv * gw[e * DIM + c * 64 + lane];
    }
#pragma unroll
    for (int e = 0; e < 8; e++)
        for (int off = 32; off > 0; off >>= 1) acc[e] += __shfl_xor(acc[e], off, 64);

    float mx = acc[0];
#pragma unroll
    for (int e = 1; e < 8; e++) mx = fmaxf(mx, acc[e]);
    float p[8], s = 0.f;
#pragma unroll
    for (int e = 0; e < 8; e++) { p[e] = expf(acc[e] - mx); s += p[e]; }

    int e1 = 0;
#pragma unroll
    for (int e = 1; e < 8; e++) if (p[e] > p[e1]) e1 = e;
    int e2 = (e1 == 0) ? 1 : 0;
#pragma unroll
    for (int e = 0; e < 8; e++) if (e != e1 && p[e] > p[e2]) e2 = e;
    const float denom = p[e1] + p[e2];

    if (lane == 0) {
        tok_e[2 * n] = e1; tok_e[2 * n + 1] = e2;
        tok_w[2 * n] = p[e1] / denom; tok_w[2 * n + 1] = p[e2] / denom;
        const float inv = 1.f / s;
#pragma unroll
        for (int e = 0; e < 8; e++) atomicAdd(&ps[e], p[e] * inv);  // LDS-only
        atomicAdd(&cs[e1], 1); atomicAdd(&cs[e2], 1);               // LDS-only
    }
    __syncthreads();
    if (threadIdx.x < 8) {
        ps_part[bid * 8 + threadIdx.x] = ps[threadIdx.x];
        cs_part[bid * 8 + threadIdx.x] = cs[threadIdx.x];
    }
}

// ---------------- finalize + scatter (single block, LDS cursors) ----------------
__global__ __launch_bounds__(256) void finalize_scatter(
    const int* cs_part, const float* ps_part,
    const int* __restrict__ tok_e, const float* __restrict__ tok_w,
    int* __restrict__ counts, int* __restrict__ off_pad,
    int* perm_tok, int* inv_pos, float* __restrict__ out_loss)
{
    __shared__ float rps[256];
    __shared__ int rcs[256];
    __shared__ int s_cur[8];
    const int t = threadIdx.x;
    const int e = t & 7, chunk = t >> 3;
    float psum = 0.f; int csum = 0;
#pragma unroll
    for (int i = 0; i < 32; i++) {
        const int b = chunk * 32 + i;
        psum += ps_part[b * 8 + e];
        csum += cs_part[b * 8 + e];
    }
    rps[t] = psum; rcs[t] = csum;
    __syncthreads();
    for (int s = 128; s >= 8; s >>= 1) {
        if (t < s) { rps[t] += rps[t + s]; rcs[t] += rcs[t + s]; }
        __syncthreads();
    }
    if (t == 0) {
        int off = 0; float loss = 0.f;
        for (int k = 0; k < 8; k++) {
            counts[k] = rcs[k];
            off_pad[k] = off; s_cur[k] = off;
            off += ((rcs[k] + 127) & ~127);
            loss += rps[k] * (float)rcs[k];
        }
        off_pad[8] = off;
        *out_loss = loss * 8.f / ((float)N_TOK * (float)N_TOK);
    }
    __syncthreads();
    for (int r = 0; r < N_TOK / 256; r++) {
        const int n = r * 256 + t;
#pragma unroll
        for (int k = 0; k < 2; k++) {
            const int ee = tok_e[2 * n + k];
            const int pos = atomicAdd(&s_cur[ee], 1);   // LDS cursor
            perm_tok[pos] = n;
            inv_pos[2 * n + k] = pos;
        }
    }
}

// ---------------- gather permuted tokens, fp32 -> bf16, zero pad rows ----------------
__global__ __launch_bounds__(256) void gather_x_kernel(
    const float* __restrict__ x, const int* __restrict__ off_pad,
    const int* __restrict__ counts, const int* __restrict__ perm_tok,
    bf16_t* __restrict__ xp)
{
    __shared__ int so[9], scnt[8];
    if (threadIdx.x < 9) so[threadIdx.x] = off_pad[threadIdx.x];
    if (threadIdx.x < 8) scnt[threadIdx.x] = counts[threadIdx.x];
    __syncthreads();
    const int gid = blockIdx.x * 256 + threadIdx.x;
    const int p = gid / 192;            // padded row
    const int c = (gid - p * 192) * 4;  // column
    int e = 0;
#pragma unroll
    for (int k = 1; k < 8; k++) if (p >= so[k]) e = k;
    const bool valid = (p < so[8]) && (p - so[e] < scnt[e]);
    float4 v = make_float4(0.f, 0.f, 0.f, 0.f);
    if (valid) {
        const int tok = perm_tok[p];
        v = *(const float4*)(x + (size_t)tok * DIM + c);
    }
    bf16x4 o; o[0] = (bf16_t)v.x; o[1] = (bf16_t)v.y; o[2] = (bf16_t)v.z; o[3] = (bf16_t)v.w;
    *(bf16x4*)(xp + (size_t)p * DIM + c) = o;
}

// ---------------- GEMM1: h = relu(xp @ w_fc^T)^2  (+ trailing wpj convert) ----------------
// 128x128 tile, BK=64, XOR-swizzled LDS (128B row stride: measured 0 conflicts).
// __launch_bounds__(256,4): VGPR 68 and LDS 32KB both fit 4 blocks/CU; the
// 2-barrier single-buffer loop hides its barrier drain only via inter-block
// overlap, so 3->4 resident blocks attacks the 80% non-MFMA time directly.
// blocks [0, GEMM1_BLOCKS): id = xcd + 8*slot, xcd = expert; slot = n_t*MMAX + m_t.
// blocks [GEMM1_BLOCKS, +CONVH_BLOCKS): convert w_proj (tail-shadow overlap).
__global__ __launch_bounds__(256, 4) void gemm1_kernel(
    const bf16_t* __restrict__ xp, const bf16_t* __restrict__ wfc,
    const int* __restrict__ off_pad, bf16_t* __restrict__ h,
    const float* __restrict__ w_proj, bf16_t* __restrict__ wpj_b)
{
    const int id = blockIdx.x;
    if (id >= GEMM1_BLOCKS) {
        convert_chunk(w_proj, wpj_b, id - GEMM1_BLOCKS, threadIdx.x);
        return;
    }
    const int e = id & 7;
    const int slot = id >> 3;
    const int n_t = slot / MMAX, m_t = slot % MMAX;

    const int seg0 = off_pad[e];
    const int cnt_pad = off_pad[e + 1] - seg0;
    const int m0 = m_t * 128;
    if (m0 >= cnt_pad) return;
    const int n0 = n_t * 128;  // over HID

    __shared__ bf16_t As[128 * 64];
    __shared__ bf16_t Bs[128 * 64];

    const int t = threadIdx.x;
    const int srow = t >> 3, sc = t & 7;
    const int gsc = sc ^ (srow & 7);   // swizzled global chunk -> linear LDS slot
    const bf16_t* abase = xp + (size_t)(seg0 + m0 + srow) * DIM + gsc * 8;
    const bf16_t* bbase = wfc + ((size_t)e * HID + n0 + srow) * DIM + gsc * 8;

    const int wv = t >> 6, lane = t & 63;
    const int lrow = lane & 15, quad = lane >> 4;
    const int wm = (wv & 1) * 64, wn = (wv >> 1) * 64;
    const int sw = lrow & 7;           // read-side swizzle key

    f32x4 acc[4][4] = {};

    for (int k0 = 0; k0 < DIM; k0 += 64) {
        __syncthreads();
#pragma unroll
        for (int ii = 0; ii < 4; ii++) {
            async_copy16(abase + (size_t)ii * 32 * DIM + k0, &As[(ii * 256 + t) * 8]);
            async_copy16(bbase + (size_t)ii * 32 * DIM + k0, &Bs[(ii * 256 + t) * 8]);
        }
        __syncthreads();
#pragma unroll
        for (int kh = 0; kh < 2; kh++) {
            const int ch = ((kh * 4 + quad) ^ sw) * 8;
            bf16x8 af[4], bfv[4];
#pragma unroll
            for (int i = 0; i < 4; i++)
                af[i] = *(bf16x8*)&As[(wm + i * 16 + lrow) * 64 + ch];
#pragma unroll
            for (int j = 0; j < 4; j++)
                bfv[j] = *(bf16x8*)&Bs[(wn + j * 16 + lrow) * 64 + ch];
#pragma unroll
            for (int i = 0; i < 4; i++)
#pragma unroll
                for (int j = 0; j < 4; j++)
                    acc[i][j] = __builtin_amdgcn_mfma_f32_16x16x32_bf16(af[i], bfv[j], acc[i][j], 0, 0, 0);
        }
    }

    // epilogue: relu^2 -> bf16. C/D map: col=lane&15 (n), row=quad*4+reg (m).
#pragma unroll
    for (int i = 0; i < 4; i++) {
#pragma unroll
        for (int g = 0; g < 4; g++) {
            const int m = m0 + wm + i * 16 + quad * 4 + g;
            bf16_t* hrow = h + (size_t)(seg0 + m) * HID + n0 + wn + lrow;
#pragma unroll
            for (int j = 0; j < 4; j++) {
                float v = fmaxf(acc[i][j][g], 0.f);
                hrow[j * 16] = (bf16_t)(v * v);
            }
        }
    }
}

// ---------------- GEMM2: y[pos] = h[pos] @ w_proj^T  (no atomics) ----------------
// 64x128 tile, BK=128 as TWO K-panels of [rows][64] (128B stride, conflict-free).
// id = xcd + 8*slot, xcd = expert; slot = m_t*6 + n_t.
__global__ __launch_bounds__(256, 3) void gemm2_kernel(
    const bf16_t* __restrict__ h, const bf16_t* __restrict__ wpj,
    const int* __restrict__ off_pad, const int* __restrict__ counts,
    bf16_t* __restrict__ y)
{
    const int id = blockIdx.x;
    const int e = id & 7;
    const int slot = id >> 3;
    const int m_t = slot / 6, n_t = slot % 6;

    const int seg0 = off_pad[e];
    const int cnt = counts[e];
    const int m0 = m_t * 64;
    if (m0 >= cnt) return;
    const int n0 = n_t * 128;  // over DIM

    __shared__ bf16_t As[2][64 * 64];    // panel p: K elems [k0+p*64, k0+p*64+64)
    __shared__ bf16_t Bs[2][128 * 64];   // 48 KB total

    const int t = threadIdx.x;
    const int srow = t >> 3, sc = t & 7;      // 8 lanes x 16B = one 128B row
    const int gsc = sc ^ (srow & 7);
    const bf16_t* abase = h + (size_t)(seg0 + m0 + srow) * HID + gsc * 8;
    const bf16_t* bbase = wpj + ((size_t)e * DIM + n0 + srow) * HID + gsc * 8;

    const int wv = t >> 6, lane = t & 63;
    const int lrow = lane & 15, quad = lane >> 4;
    const int wm = (wv & 1) * 32, wn = (wv >> 1) * 64;   // 2x2 waves, 32x64 each
    const int sw = lrow & 7;

    f32x4 acc[2][4] = {};

    for (int k0 = 0; k0 < HID; k0 += 128) {
        __syncthreads();
#pragma unroll
        for (int p = 0; p < 2; p++) {
#pragma unroll
            for (int ii = 0; ii < 2; ii++)   // A: 64 rows (2 passes of 32)
                async_copy16(abase + (size_t)ii * 32 * HID + k0 + p * 64,
                             &As[p][(ii * 256 + t) * 8]);
#pragma unroll
            for (int ii = 0; ii < 4; ii++)   // B: 128 rows (4 passes of 32)
                async_copy16(bbase + (size_t)ii * 32 * HID + k0 + p * 64,
                             &Bs[p][(ii * 256 + t) * 8]);
        }
        __syncthreads();
#pragma unroll
        for (int kh = 0; kh < 4; kh++) {
            const int p = kh >> 1, khh = kh & 1;
            const int ch = ((khh * 4 + quad) ^ sw) * 8;
            bf16x8 af[2], bfv[4];
#pragma unroll
            for (int i = 0; i < 2; i++)
                af[i] = *(bf16x8*)&As[p][(wm + i * 16 + lrow) * 64 + ch];
#pragma unroll
            for (int j = 0; j < 4; j++)
                bfv[j] = *(bf16x8*)&Bs[p][(wn + j * 16 + lrow) * 64 + ch];
#pragma unroll
            for (int i = 0; i < 2; i++)
#pragma unroll
                for (int j = 0; j < 4; j++)
                    acc[i][j] = __builtin_amdgcn_mfma_f32_16x16x32_bf16(af[i], bfv[j], acc[i][j], 0, 0, 0);
        }
    }

    // epilogue: plain bf16 stores, rows exclusive to this block
#pragma unroll
    for (int i = 0; i < 2; i++) {
#pragma unroll
        for (int g = 0; g < 4; g++) {
            const int m = m0 + wm + i * 16 + quad * 4 + g;
            if (m < cnt) {
                bf16_t* yrow = y + (size_t)(seg0 + m) * DIM + n0 + wn + lrow;
#pragma unroll
                for (int j = 0; j < 4; j++)
                    yrow[j * 16] = (bf16_t)acc[i][j][g];
            }
        }
    }
}

// ---------------- combine: out[n] = w1*y[p1] + w2*y[p2] ----------------
__global__ __launch_bounds__(192) void combine_kernel(
    const bf16_t* __restrict__ y, const int* __restrict__ inv_pos,
    const float* __restrict__ tok_w, float* __restrict__ out)
{
    const int n = blockIdx.x;
    const int d = threadIdx.x * 4;
    const int p1 = inv_pos[2 * n], p2 = inv_pos[2 * n + 1];
    const float w1 = tok_w[2 * n], w2 = tok_w[2 * n + 1];
    bf16x4 a = *(const bf16x4*)(y + (size_t)p1 * DIM + d);
    bf16x4 b = *(const bf16x4*)(y + (size_t)p2 * DIM + d);
    float4 o;
    o.x = w1 * (float)a[0] + w2 * (float)b[0];
    o.y = w1 * (float)a[1] + w2 * (float)b[1];
    o.z = w1 * (float)a[2] + w2 * (float)b[2];
    o.w = w1 * (float)a[3] + w2 * (float)b[3];
    *(float4*)(out + (size_t)n * DIM + d) = o;
}

extern "C" void kernel_launch(void* const* d_in, const int* in_sizes, int n_in,
                              void* d_out, int out_size, void* d_ws, size_t ws_size,
                              hipStream_t stream) {
    const float* x      = (const float*)d_in[0];
    const float* gate_w = (const float*)d_in[1];
    const float* w_fc   = (const float*)d_in[2];
    const float* w_proj = (const float*)d_in[3];
    float* out = (float*)d_out;

    if (ws_size < WS_NEEDED) return;

    char* w = (char*)d_ws;
    int*    counts    = (int*)(w + OFF_COUNTS);
    int*    off_pad   = (int*)(w + OFF_OFFPAD);
    int*    tok_e     = (int*)(w + OFF_TOKE);
    float*  tok_w     = (float*)(w + OFF_TOKW);
    int*    perm_tok  = (int*)(w + OFF_PERMT);
    int*    inv_pos   = (int*)(w + OFF_PERMW);   // ps_part then inv_pos
    bf16_t* xp        = (bf16_t*)(w + OFF_XP);   // xp, then y (gemm2 output)
    bf16_t* wfc_b     = (bf16_t*)(w + OFF_WFC);
    bf16_t* wpj_b     = (bf16_t*)(w + OFF_WPJ);
    bf16_t* hbuf      = (bf16_t*)(w + OFF_H);

    int*   cs_part = perm_tok;            // int[1024*8], consumed by finalize
    float* ps_part = (float*)inv_pos;     // float[1024*8], consumed by finalize
    bf16_t* y = xp;                       // xp dead after gemm1

    // no d_out memset: combine writes every [0, N*DIM) element, loss at out_size-1
    // (verified passing in round 7).
    prep_kernel<<<GATE_BLOCKS + CONVH_BLOCKS, 256, 0, stream>>>(
        w_fc, wfc_b, x, gate_w, cs_part, ps_part, tok_e, tok_w);
    finalize_scatter<<<1, 256, 0, stream>>>(cs_part, ps_part, tok_e, tok_w,
                                            counts, off_pad, perm_tok, inv_pos,
                                            out + (size_t)out_size - 1);
    gather_x_kernel<<<PADROWS * DIM / 4 / 256, 256, 0, stream>>>(x, off_pad, counts, perm_tok, xp);

    // gemm1 + trailing w_proj-convert blocks (overlap; done before gemm2 by ordering)
    gemm1_kernel<<<GEMM1_BLOCKS + CONVH_BLOCKS, 256, 0, stream>>>(
        xp, wfc_b, off_pad, hbuf, w_proj, wpj_b);
    gemm2_kernel<<<8 * MT2 * 6, 256, 0, stream>>>(hbuf, wpj_b, off_pad, counts, y);
    combine_kernel<<<N_TOK, 192, 0, stream>>>(y, inv_pos, tok_w, out);
}

// Round 11
// 297.912 us; speedup vs baseline: 1.2705x; 1.0665x over previous
//
#include <hip/hip_runtime.h>
#include <hip/hip_bf16.h>

typedef __bf16 bf16_t;
typedef bf16_t bf16x8 __attribute__((ext_vector_type(8)));
typedef bf16_t bf16x4 __attribute__((ext_vector_type(4)));
typedef float f32x4 __attribute__((ext_vector_type(4)));

#define N_TOK 4096
#define DIM   768
#define HID   3072
#define NEXP  8
#define PADROWS 9216   // 8192 + 8*128 headroom for per-expert 128-padding
#define MMAX  32       // 128-row m-tiles per expert

// ---------------- ws layout (bytes) ----------------
#define OFF_COUNTS 0
#define OFF_PSUM   32
#define OFF_OFFPAD 64      // int off_pad[9]
#define OFF_CURSOR 128
#define OFF_TOKE   256                         // int[8192]
#define OFF_TOKW   (OFF_TOKE + 4*8192)         // float[8192]
#define OFF_PERMT  (OFF_TOKW + 4*8192)         // int[PADROWS]  (also cs_part)
#define OFF_PERMW  (OFF_PERMT + 4*PADROWS)     // float[PADROWS] (ps_part, then inv_pos)
#define OFF_XP     (((OFF_PERMW + 4*PADROWS) + 511) & ~511ull)  // bf16[PADROWS*DIM] (xp, then y0)
#define OFF_WFC    (OFF_XP + 2ull*PADROWS*DIM)                  // bf16[8*HID*DIM] (wfc_b, then y1)
#define OFF_WPJ    (OFF_WFC + 2ull*NEXP*HID*DIM)                // bf16[8*DIM*HID]
#define OFF_H      (OFF_WPJ + 2ull*NEXP*DIM*HID)                // bf16[PADROWS*HID]
#define WS_NEEDED  (OFF_H + 2ull*PADROWS*HID)

#define GATE_BLOCKS (N_TOK / 4)    // 1024
#define CONVH_BLOCKS 4608          // blocks to convert ONE weight tensor
#define GEMM1_BLOCKS (8 * 24 * MMAX)   // 6144

// ---------------- async global->LDS 16B ----------------
__device__ __forceinline__ void async_copy16(const bf16_t* g, bf16_t* l) {
    __builtin_amdgcn_global_load_lds(
        (const __attribute__((address_space(1))) void*)g,
        (__attribute__((address_space(3))) void*)l, 16, 0, 0);
}

// ---------------- fp32 -> bf16 tensor convert, fully coalesced ----------------
// R7 lesson: keep pre-conversion (fp32-direct GEMM doubles HBM + overflows L2).
// Loads are NONTEMPORAL via clang ext-vector f32x4 (__builtin_nontemporal_load
// rejects HIP_vector_type float4). fp32 weights are read exactly once; keep
// them out of L2/L3 so the caches hold bf16 weights/h (R8 FETCH shows bf16
// reads are L3-served). Stores stay cacheable for exactly that reason.
__device__ __forceinline__ void convert_chunk(const float* __restrict__ src,
                                              bf16_t* __restrict__ dst,
                                              int cid, int t) {
    const long long base = (long long)cid * 256 + t;          // float4 index
    const long long stride = (long long)CONVH_BLOCKS * 256;   // 1179648
    // 18874368 floats / 4 = 4718592 float4 = exactly 4 * stride
#pragma unroll
    for (int it = 0; it < 4; it++) {
        const long long i4 = base + (long long)it * stride;
        f32x4 v = __builtin_nontemporal_load(((const f32x4*)src) + i4);
        bf16x4 o;
        o[0] = (bf16_t)v.x; o[1] = (bf16_t)v.y;
        o[2] = (bf16_t)v.z; o[3] = (bf16_t)v.w;
        *(bf16x4*)(dst + i4 * 4) = o;
    }
}

// ---------------- fused prep: gating + w_fc convert ----------------
__global__ __launch_bounds__(256) void prep_kernel(
    const float* __restrict__ w_fc, bf16_t* __restrict__ wfc_b,
    const float* __restrict__ x, const float* __restrict__ gw,
    int* __restrict__ cs_part, float* __restrict__ ps_part,
    int* __restrict__ tok_e, float* __restrict__ tok_w)
{
    __shared__ float ps[8];
    __shared__ int cs[8];

    if (blockIdx.x >= GATE_BLOCKS) {
        convert_chunk(w_fc, wfc_b, blockIdx.x - GATE_BLOCKS, threadIdx.x);
        return;
    }

    // ---- gate path ----
    if (threadIdx.x < 8) { ps[threadIdx.x] = 0.f; cs[threadIdx.x] = 0; }
    __syncthreads();

    const int bid = blockIdx.x;
    const int wv = threadIdx.x >> 6, lane = threadIdx.x & 63;
    const int n = bid * 4 + wv;

    float acc[8];
#pragma unroll
    for (int e = 0; e < 8; e++) acc[e] = 0.f;
    const float* xr = x + (size_t)n * DIM;
#pragma unroll
    for (int c = 0; c < 12; c++) {
        const float xv = xr[c * 64 + lane];
#pragma unroll
        for (int e = 0; e < 8; e++) acc[e] += xv * gw[e * DIM + c * 64 + lane];
    }
#pragma unroll
    for (int e = 0; e < 8; e++)
        for (int off = 32; off > 0; off >>= 1) acc[e] += __shfl_xor(acc[e], off, 64);

    float mx = acc[0];
#pragma unroll
    for (int e = 1; e < 8; e++) mx = fmaxf(mx, acc[e]);
    float p[8], s = 0.f;
#pragma unroll
    for (int e = 0; e < 8; e++) { p[e] = expf(acc[e] - mx); s += p[e]; }

    int e1 = 0;
#pragma unroll
    for (int e = 1; e < 8; e++) if (p[e] > p[e1]) e1 = e;
    int e2 = (e1 == 0) ? 1 : 0;
#pragma unroll
    for (int e = 0; e < 8; e++) if (e != e1 && p[e] > p[e2]) e2 = e;
    const float denom = p[e1] + p[e2];

    if (lane == 0) {
        tok_e[2 * n] = e1; tok_e[2 * n + 1] = e2;
        tok_w[2 * n] = p[e1] / denom; tok_w[2 * n + 1] = p[e2] / denom;
        const float inv = 1.f / s;
#pragma unroll
        for (int e = 0; e < 8; e++) atomicAdd(&ps[e], p[e] * inv);  // LDS-only
        atomicAdd(&cs[e1], 1); atomicAdd(&cs[e2], 1);               // LDS-only
    }
    __syncthreads();
    if (threadIdx.x < 8) {
        ps_part[bid * 8 + threadIdx.x] = ps[threadIdx.x];
        cs_part[bid * 8 + threadIdx.x] = cs[threadIdx.x];
    }
}

// ---------------- finalize + scatter (single block, LDS cursors) ----------------
__global__ __launch_bounds__(256) void finalize_scatter(
    const int* cs_part, const float* ps_part,
    const int* __restrict__ tok_e, const float* __restrict__ tok_w,
    int* __restrict__ counts, int* __restrict__ off_pad,
    int* perm_tok, int* inv_pos, float* __restrict__ out_loss)
{
    __shared__ float rps[256];
    __shared__ int rcs[256];
    __shared__ int s_cur[8];
    const int t = threadIdx.x;
    const int e = t & 7, chunk = t >> 3;
    float psum = 0.f; int csum = 0;
#pragma unroll
    for (int i = 0; i < 32; i++) {
        const int b = chunk * 32 + i;
        psum += ps_part[b * 8 + e];
        csum += cs_part[b * 8 + e];
    }
    rps[t] = psum; rcs[t] = csum;
    __syncthreads();
    for (int s = 128; s >= 8; s >>= 1) {
        if (t < s) { rps[t] += rps[t + s]; rcs[t] += rcs[t + s]; }
        __syncthreads();
    }
    if (t == 0) {
        int off = 0; float loss = 0.f;
        for (int k = 0; k < 8; k++) {
            counts[k] = rcs[k];
            off_pad[k] = off; s_cur[k] = off;
            off += ((rcs[k] + 127) & ~127);
            loss += rps[k] * (float)rcs[k];
        }
        off_pad[8] = off;
        *out_loss = loss * 8.f / ((float)N_TOK * (float)N_TOK);
    }
    __syncthreads();
    for (int r = 0; r < N_TOK / 256; r++) {
        const int n = r * 256 + t;
#pragma unroll
        for (int k = 0; k < 2; k++) {
            const int ee = tok_e[2 * n + k];
            const int pos = atomicAdd(&s_cur[ee], 1);   // LDS cursor
            perm_tok[pos] = n;
            inv_pos[2 * n + k] = pos;
        }
    }
}

// ---------------- gather permuted tokens, fp32 -> bf16, zero pad rows ----------------
__global__ __launch_bounds__(256) void gather_x_kernel(
    const float* __restrict__ x, const int* __restrict__ off_pad,
    const int* __restrict__ counts, const int* __restrict__ perm_tok,
    bf16_t* __restrict__ xp)
{
    __shared__ int so[9], scnt[8];
    if (threadIdx.x < 9) so[threadIdx.x] = off_pad[threadIdx.x];
    if (threadIdx.x < 8) scnt[threadIdx.x] = counts[threadIdx.x];
    __syncthreads();
    const int gid = blockIdx.x * 256 + threadIdx.x;
    const int p = gid / 192;            // padded row
    const int c = (gid - p * 192) * 4;  // column
    int e = 0;
#pragma unroll
    for (int k = 1; k < 8; k++) if (p >= so[k]) e = k;
    const bool valid = (p < so[8]) && (p - so[e] < scnt[e]);
    float4 v = make_float4(0.f, 0.f, 0.f, 0.f);
    if (valid) {
        const int tok = perm_tok[p];
        v = *(const float4*)(x + (size_t)tok * DIM + c);
    }
    bf16x4 o; o[0] = (bf16_t)v.x; o[1] = (bf16_t)v.y; o[2] = (bf16_t)v.z; o[3] = (bf16_t)v.w;
    *(bf16x4*)(xp + (size_t)p * DIM + c) = o;
}

// ---------------- GEMM1: h = relu(xp @ w_fc^T)^2  (+ trailing wpj convert) ----------------
// 128x128 tile, BK=64, XOR-swizzled LDS (128B row stride: measured 0 conflicts).
// blocks [0, GEMM1_BLOCKS): id = xcd + 8*slot, xcd = expert; slot = n_t*MMAX + m_t.
// blocks [GEMM1_BLOCKS, +CONVH_BLOCKS): convert w_proj (tail-shadow overlap).
__global__ __launch_bounds__(256, 4) void gemm1_kernel(
    const bf16_t* __restrict__ xp, const bf16_t* __restrict__ wfc,
    const int* __restrict__ off_pad, bf16_t* __restrict__ h,
    const float* __restrict__ w_proj, bf16_t* __restrict__ wpj_b)
{
    const int id = blockIdx.x;
    if (id >= GEMM1_BLOCKS) {
        convert_chunk(w_proj, wpj_b, id - GEMM1_BLOCKS, threadIdx.x);
        return;
    }
    const int e = id & 7;
    const int slot = id >> 3;
    const int n_t = slot / MMAX, m_t = slot % MMAX;

    const int seg0 = off_pad[e];
    const int cnt_pad = off_pad[e + 1] - seg0;
    const int m0 = m_t * 128;
    if (m0 >= cnt_pad) return;
    const int n0 = n_t * 128;  // over HID

    __shared__ bf16_t As[128 * 64];
    __shared__ bf16_t Bs[128 * 64];

    const int t = threadIdx.x;
    const int srow = t >> 3, sc = t & 7;
    const int gsc = sc ^ (srow & 7);   // swizzled global chunk -> linear LDS slot
    const bf16_t* abase = xp + (size_t)(seg0 + m0 + srow) * DIM + gsc * 8;
    const bf16_t* bbase = wfc + ((size_t)e * HID + n0 + srow) * DIM + gsc * 8;

    const int wv = t >> 6, lane = t & 63;
    const int lrow = lane & 15, quad = lane >> 4;
    const int wm = (wv & 1) * 64, wn = (wv >> 1) * 64;
    const int sw = lrow & 7;           // read-side swizzle key

    f32x4 acc[4][4] = {};

    for (int k0 = 0; k0 < DIM; k0 += 64) {
        __syncthreads();
#pragma unroll
        for (int ii = 0; ii < 4; ii++) {
            async_copy16(abase + (size_t)ii * 32 * DIM + k0, &As[(ii * 256 + t) * 8]);
            async_copy16(bbase + (size_t)ii * 32 * DIM + k0, &Bs[(ii * 256 + t) * 8]);
        }
        __syncthreads();
#pragma unroll
        for (int kh = 0; kh < 2; kh++) {
            const int ch = ((kh * 4 + quad) ^ sw) * 8;
            bf16x8 af[4], bfv[4];
#pragma unroll
            for (int i = 0; i < 4; i++)
                af[i] = *(bf16x8*)&As[(wm + i * 16 + lrow) * 64 + ch];
#pragma unroll
            for (int j = 0; j < 4; j++)
                bfv[j] = *(bf16x8*)&Bs[(wn + j * 16 + lrow) * 64 + ch];
#pragma unroll
            for (int i = 0; i < 4; i++)
#pragma unroll
                for (int j = 0; j < 4; j++)
                    acc[i][j] = __builtin_amdgcn_mfma_f32_16x16x32_bf16(af[i], bfv[j], acc[i][j], 0, 0, 0);
        }
    }

    // epilogue: relu^2 -> bf16. C/D map: col=lane&15 (n), row=quad*4+reg (m).
#pragma unroll
    for (int i = 0; i < 4; i++) {
#pragma unroll
        for (int g = 0; g < 4; g++) {
            const int m = m0 + wm + i * 16 + quad * 4 + g;
            bf16_t* hrow = h + (size_t)(seg0 + m) * HID + n0 + wn + lrow;
#pragma unroll
            for (int j = 0; j < 4; j++) {
                float v = fmaxf(acc[i][j][g], 0.f);
                hrow[j * 16] = (bf16_t)(v * v);
            }
        }
    }
}

// ---------------- GEMM2: y-partials = h @ w_proj^T, split-K=2, NO atomics ----------------
// Proven 128x128/BK=64 structure (compute:staging 1.0 vs 0.67 for the old
// 64x128/BK=128). split=0 -> y0, split=1 -> y1 (separate buffers, plain
// bf16 stores; combine sums in f32). ~768 working blocks.
// id = xcd + 8*slot, xcd = expert; slot = split*(MMAX*6) + m_t*6 + n_t.
__global__ __launch_bounds__(256, 4) void gemm2_kernel(
    const bf16_t* __restrict__ h, const bf16_t* __restrict__ wpj,
    const int* __restrict__ off_pad, const int* __restrict__ counts,
    bf16_t* __restrict__ y0, bf16_t* __restrict__ y1)
{
    const int id = blockIdx.x;
    const int e = id & 7;
    const int slot = id >> 3;
    const int split = slot / (MMAX * 6);
    const int rem = slot % (MMAX * 6);
    const int m_t = rem / 6, n_t = rem % 6;

    const int seg0 = off_pad[e];
    const int cnt = counts[e];
    const int m0 = m_t * 128;
    if (m0 >= cnt) return;
    const int n0 = n_t * 128;  // over DIM
    const int kbeg = split * (HID / 2);

    __shared__ bf16_t As[128 * 64];
    __shared__ bf16_t Bs[128 * 64];

    const int t = threadIdx.x;
    const int srow = t >> 3, sc = t & 7;
    const int gsc = sc ^ (srow & 7);
    const bf16_t* abase = h + (size_t)(seg0 + m0 + srow) * HID + kbeg + gsc * 8;
    const bf16_t* bbase = wpj + ((size_t)e * DIM + n0 + srow) * HID + kbeg + gsc * 8;

    const int wv = t >> 6, lane = t & 63;
    const int lrow = lane & 15, quad = lane >> 4;
    const int wm = (wv & 1) * 64, wn = (wv >> 1) * 64;
    const int sw = lrow & 7;

    f32x4 acc[4][4] = {};

    for (int k0 = 0; k0 < HID / 2; k0 += 64) {
        __syncthreads();
#pragma unroll
        for (int ii = 0; ii < 4; ii++) {
            async_copy16(abase + (size_t)ii * 32 * HID + k0, &As[(ii * 256 + t) * 8]);
            async_copy16(bbase + (size_t)ii * 32 * HID + k0, &Bs[(ii * 256 + t) * 8]);
        }
        __syncthreads();
#pragma unroll
        for (int kh = 0; kh < 2; kh++) {
            const int ch = ((kh * 4 + quad) ^ sw) * 8;
            bf16x8 af[4], bfv[4];
#pragma unroll
            for (int i = 0; i < 4; i++)
                af[i] = *(bf16x8*)&As[(wm + i * 16 + lrow) * 64 + ch];
#pragma unroll
            for (int j = 0; j < 4; j++)
                bfv[j] = *(bf16x8*)&Bs[(wn + j * 16 + lrow) * 64 + ch];
#pragma unroll
            for (int i = 0; i < 4; i++)
#pragma unroll
                for (int j = 0; j < 4; j++)
                    acc[i][j] = __builtin_amdgcn_mfma_f32_16x16x32_bf16(af[i], bfv[j], acc[i][j], 0, 0, 0);
        }
    }

    bf16_t* yout = split ? y1 : y0;
#pragma unroll
    for (int i = 0; i < 4; i++) {
#pragma unroll
        for (int g = 0; g < 4; g++) {
            const int m = m0 + wm + i * 16 + quad * 4 + g;
            if (m < cnt) {
                bf16_t* yrow = yout + (size_t)(seg0 + m) * DIM + n0 + wn + lrow;
#pragma unroll
                for (int j = 0; j < 4; j++)
                    yrow[j * 16] = (bf16_t)acc[i][j][g];
            }
        }
    }
}

// ---------------- combine: out[n] = w1*(y0[p1]+y1[p1]) + w2*(y0[p2]+y1[p2]) ----------------
__global__ __launch_bounds__(192) void combine_kernel(
    const bf16_t* __restrict__ y0, const bf16_t* __restrict__ y1,
    const int* __restrict__ inv_pos, const float* __restrict__ tok_w,
    float* __restrict__ out)
{
    const int n = blockIdx.x;
    const int d = threadIdx.x * 4;
    const int p1 = inv_pos[2 * n], p2 = inv_pos[2 * n + 1];
    const float w1 = tok_w[2 * n], w2 = tok_w[2 * n + 1];
    bf16x4 a0 = *(const bf16x4*)(y0 + (size_t)p1 * DIM + d);
    bf16x4 a1 = *(const bf16x4*)(y1 + (size_t)p1 * DIM + d);
    bf16x4 b0 = *(const bf16x4*)(y0 + (size_t)p2 * DIM + d);
    bf16x4 b1 = *(const bf16x4*)(y1 + (size_t)p2 * DIM + d);
    float4 o;
    o.x = w1 * ((float)a0[0] + (float)a1[0]) + w2 * ((float)b0[0] + (float)b1[0]);
    o.y = w1 * ((float)a0[1] + (float)a1[1]) + w2 * ((float)b0[1] + (float)b1[1]);
    o.z = w1 * ((float)a0[2] + (float)a1[2]) + w2 * ((float)b0[2] + (float)b1[2]);
    o.w = w1 * ((float)a0[3] + (float)a1[3]) + w2 * ((float)b0[3] + (float)b1[3]);
    *(float4*)(out + (size_t)n * DIM + d) = o;
}

extern "C" void kernel_launch(void* const* d_in, const int* in_sizes, int n_in,
                              void* d_out, int out_size, void* d_ws, size_t ws_size,
                              hipStream_t stream) {
    const float* x      = (const float*)d_in[0];
    const float* gate_w = (const float*)d_in[1];
    const float* w_fc   = (const float*)d_in[2];
    const float* w_proj = (const float*)d_in[3];
    float* out = (float*)d_out;

    if (ws_size < WS_NEEDED) return;

    char* w = (char*)d_ws;
    int*    counts    = (int*)(w + OFF_COUNTS);
    int*    off_pad   = (int*)(w + OFF_OFFPAD);
    int*    tok_e     = (int*)(w + OFF_TOKE);
    float*  tok_w     = (float*)(w + OFF_TOKW);
    int*    perm_tok  = (int*)(w + OFF_PERMT);
    int*    inv_pos   = (int*)(w + OFF_PERMW);   // ps_part then inv_pos
    bf16_t* xp        = (bf16_t*)(w + OFF_XP);   // xp, then y0 (gemm2 split-0 out)
    bf16_t* wfc_b     = (bf16_t*)(w + OFF_WFC);  // wfc_b, then y1 (gemm2 split-1 out)
    bf16_t* wpj_b     = (bf16_t*)(w + OFF_WPJ);
    bf16_t* hbuf      = (bf16_t*)(w + OFF_H);

    int*   cs_part = perm_tok;            // int[1024*8], consumed by finalize
    float* ps_part = (float*)inv_pos;     // float[1024*8], consumed by finalize
    bf16_t* y0 = xp;                      // xp dead after gemm1
    bf16_t* y1 = wfc_b;                   // wfc_b dead after gemm1 (14.2MB < 37.7MB)

    // no d_out memset: combine writes every [0, N*DIM) element, loss at out_size-1.
    prep_kernel<<<GATE_BLOCKS + CONVH_BLOCKS, 256, 0, stream>>>(
        w_fc, wfc_b, x, gate_w, cs_part, ps_part, tok_e, tok_w);
    finalize_scatter<<<1, 256, 0, stream>>>(cs_part, ps_part, tok_e, tok_w,
                                            counts, off_pad, perm_tok, inv_pos,
                                            out + (size_t)out_size - 1);
    gather_x_kernel<<<PADROWS * DIM / 4 / 256, 256, 0, stream>>>(x, off_pad, counts, perm_tok, xp);

    // gemm1 + trailing w_proj-convert blocks (overlap; done before gemm2 by ordering)
    gemm1_kernel<<<GEMM1_BLOCKS + CONVH_BLOCKS, 256, 0, stream>>>(
        xp, wfc_b, off_pad, hbuf, w_proj, wpj_b);
    gemm2_kernel<<<8 * 2 * MMAX * 6, 256, 0, stream>>>(hbuf, wpj_b, off_pad, counts, y0, y1);
    combine_kernel<<<N_TOK, 192, 0, stream>>>(y0, y1, inv_pos, tok_w, out);
}